// Round 18
// baseline (590.529 us; speedup 1.0000x reference)
//
#include <hip/hip_runtime.h>

typedef _Float16 f16;
typedef _Float16 f16x2 __attribute__((ext_vector_type(2)));
typedef _Float16 f16x4 __attribute__((ext_vector_type(4)));
typedef _Float16 f16x8 __attribute__((ext_vector_type(8)));
typedef float f32x4 __attribute__((ext_vector_type(4)));

// ---- f16 weight arena in d_ws (units: halfs) ----
// [0, 77824): LDS image (ALL matmul weights), kappa-permuted + XOR-swizzled.
#define L_W1   0             // s1_w *30/2pi   [128][64]
#define L_W2   8192          // s2_w *30/2pi   [256][128]
#define L_WF1  40960         // fc1_w          [64][256]
#define L_WF2  57344         // fc2_w          [64][64]
#define L_WF3  61440         // fc3_w          [256][64]
#define LIMG   77824         // LDS image halfs (155648 B)
#define OFF_WGE 77824        // [16][288] kappa-permuted: rows 0-6 gate, 8-14 experts (L2)
#define OFF_WP2 82432        // p2_w *30/2pi  [32][32] kappa-permuted (L2)
#define TOTH    83456
// ---- fp32 arena at (float*)(ws + TOTH) ----
#define FB_B1  0
#define FB_B2  128
#define FB_F1  384
#define FB_F2  448
#define FB_F3  512
#define FB_GE  768           // gate_b(0..6), 0, exp_b(8..14), 0
#define FB_P2  784
#define FB_PEW 816           // pe_w * 1/2pi   [32][4]
#define FB_PEB 944           // pe_b * 1/2pi   [32]
#define FB_P1W 976           // p1_w * 30/2pi  [32][4]
#define FB_P1B 1104          // p1_b * 30/2pi  [32]
#define FBTOT  1136

#define SIREN_SCL 4.77464829275686f   // 30/(2*pi)
#define INV2PI    0.15915494309189535f

__device__ __forceinline__ float sin_pre(float v){   // v in revolutions
  return __builtin_amdgcn_sinf(__builtin_amdgcn_fractf(v));
}
__device__ __forceinline__ int permk(int k){
  return 16 * ((k & 7) >> 2) + ((k >> 3) & 3) * 4 + (k & 3);
}

// ---------- weight conversion (identical to R10/R14) ----------
__global__ void convert_w(const float* __restrict__ s1w, const float* __restrict__ s1b,
                          const float* __restrict__ s2w, const float* __restrict__ s2b,
                          const float* __restrict__ f1w, const float* __restrict__ f1b,
                          const float* __restrict__ f2w, const float* __restrict__ f2b,
                          const float* __restrict__ f3w, const float* __restrict__ f3b,
                          const float* __restrict__ gw,  const float* __restrict__ gb,
                          const float* __restrict__ ew,  const float* __restrict__ eb,
                          const float* __restrict__ p2w, const float* __restrict__ p2b,
                          const float* __restrict__ pew, const float* __restrict__ peb,
                          const float* __restrict__ p1w, const float* __restrict__ p1b,
                          f16* __restrict__ ws)
{
  int stride = gridDim.x * blockDim.x;
  int t0 = blockIdx.x * blockDim.x + threadIdx.x;
  for (int i = t0; i < TOTH; i += stride){
    float v;
    if (i < L_W2){
      int r = i >> 6, s = i & 63, k = s ^ ((r & 7) << 3);
      v = SIREN_SCL * s1w[(r << 6) + (k & 32) + permk(k & 31)];
    } else if (i < L_WF1){
      int j = i - L_W2, r = j >> 7, s = j & 127, k = s ^ ((r & 7) << 3);
      v = SIREN_SCL * s2w[(r << 7) + (k & 96) + permk(k & 31)];
    } else if (i < L_WF2){
      int j = i - L_WF1, r = j >> 8, s = j & 255, k = s ^ ((r & 7) << 3);
      v = f1w[(r << 8) + (k & 224) + permk(k & 31)];
    } else if (i < L_WF3){
      int j = i - L_WF2, r = j >> 6, s = j & 63, k = s ^ ((r & 7) << 3);
      v = f2w[(r << 6) + (k & 32) + permk(k & 31)];
    } else if (i < OFF_WGE){
      int j = i - L_WF3, r = j >> 6, s = j & 63, k = s ^ ((r & 7) << 3);
      v = f3w[(r << 6) + (k & 32) + permk(k & 31)];
    } else if (i < OFF_WP2){
      int j = i - OFF_WGE, r = j / 288, k = j - r * 288;
      int p = (k & ~31) + permk(k & 31);
      v = (r < 7) ? gw[r * 288 + p]
        : ((r >= 8 && r < 15 && p < 256) ? ew[(r - 8) * 256 + p] : 0.f);
    } else {
      int j = i - OFF_WP2, r = j >> 5, k = j & 31;
      v = SIREN_SCL * p2w[(r << 5) + permk(k)];
    }
    ws[i] = (f16)v;
  }
  float* bws = (float*)(ws + TOTH);
  for (int i = t0; i < FBTOT; i += stride){
    float v;
    if (i < 128)      v = SIREN_SCL * s1b[i];
    else if (i < 384) v = SIREN_SCL * s2b[i - 128];
    else if (i < 448) v = f1b[i - 384];
    else if (i < 512) v = f2b[i - 448];
    else if (i < 768) v = f3b[i - 512];
    else if (i < 784){ int j = i - 768;
      v = (j < 7) ? gb[j] : ((j >= 8 && j < 15) ? eb[j - 8] : 0.0f); }
    else if (i < 816) v = SIREN_SCL * p2b[i - 784];
    else if (i < 944) v = INV2PI * pew[i - FB_PEW];
    else if (i < 976) v = INV2PI * peb[i - FB_PEB];
    else if (i < 1104) v = SIREN_SCL * p1w[i - FB_P1W];
    else v = SIREN_SCL * p1b[i - FB_P1B];
    bws[i] = v;
  }
}

// packed f32->f16x2 conversion (v_cvt_pkrtz_f16_f32: 1 inst per 2 halfs).
// Builtin returns __fp16-based vector; bit_cast to our _Float16-based type.
__device__ __forceinline__ f16x4 pk4(float a, float b, float c, float d){
  f16x2 lo = __builtin_bit_cast(f16x2, __builtin_amdgcn_cvt_pkrtz(a, b));
  f16x2 hi = __builtin_bit_cast(f16x2, __builtin_amdgcn_cvt_pkrtz(c, d));
  return __builtin_shufflevector(lo, hi, 0, 1, 2, 3);
}
__device__ __forceinline__ f16x4 sin4p(f32x4 a){
  return pk4(sin_pre(a[0]), sin_pre(a[1]), sin_pre(a[2]), sin_pre(a[3]));
}
__device__ __forceinline__ f16x4 relu4(f32x4 a){
  return pk4(fmaxf(a[0],0.f), fmaxf(a[1],0.f), fmaxf(a[2],0.f), fmaxf(a[3],0.f));
}
__device__ __forceinline__ f16x4 resrelu4(f32x4 a, f16x4 old){
  return pk4(fmaxf(a[0]+(float)old[0],0.f), fmaxf(a[1]+(float)old[1],0.f),
             fmaxf(a[2]+(float)old[2],0.f), fmaxf(a[3]+(float)old[3],0.f));
}
#define SHUF8(A_, B_) __builtin_shufflevector(A_, B_, 0, 1, 2, 3, 4, 5, 6, 7)

// In-register layer, 2 row-groups: each LDS weight fragment feeds 2 independent
// MFMA chains (g=0,1). OUTSTMT sees ct, g, acc[g].
#define LAYER_LDS(NT_, NKS_, LOFF_, BOFF_, INq_, OUTSTMT_)                        \
  _Pragma("unroll")                                                               \
  for (int ct = 0; ct < (NT_); ++ct){                                             \
    float4 b4 = *(const float4*)(bws + (BOFF_) + ct * 16 + lk * 4);               \
    f32x4 acc[2];                                                                 \
    acc[0] = (f32x4){b4.x, b4.y, b4.z, b4.w};  acc[1] = acc[0];                   \
    _Pragma("unroll")                                                             \
    for (int ks = 0; ks < (NKS_); ++ks){                                          \
      f16x8 wv = *(const f16x8*)(wlds + (LOFF_) + (ct * 16 + l15) * ((NKS_) * 32) \
                                  + ((32 * ks + 8 * lk) ^ swzh));                 \
      _Pragma("unroll")                                                           \
      for (int g = 0; g < 2; ++g){                                                \
        f16x8 bf = SHUF8((INq_)[g][2 * ks], (INq_)[g][2 * ks + 1]);               \
        acc[g] = __builtin_amdgcn_mfma_f32_16x16x32_f16(wv, bf, acc[g], 0, 0, 0); \
      }                                                                           \
    }                                                                             \
    _Pragma("unroll")                                                             \
    for (int g = 0; g < 2; ++g){ OUTSTMT_; }                                      \
  }

// R10 structure (best: 151us), persistent blocks: grid=256 (1/CU, forced by
// 152KB LDS), each block loops 8 batches of 256 rows. Weights staged ONCE;
// no barrier between batches (waves free-run). Spills (~80MB) accepted: every
// alternative (AGPR stash R14, LDS stash R13, L2 weights R13/R16) lost.
__global__ __launch_bounds__(512, 2) void moe_main(
    const float* __restrict__ x,
    const f16* __restrict__ ws, float* __restrict__ out)
{
  const float* bws = (const float*)(ws + TOTH);
  __shared__ __align__(16) f16 wlds[LIMG];   // 155648 B -> 1 block/CU, 8 waves

  const int tid = threadIdx.x;
  const int lane = tid & 63, wid = tid >> 6;
  const int l15 = lane & 15, lk = lane >> 4;
  const int swzh = (l15 & 7) << 3;           // row = ct*16+l15 -> row&7 = l15&7

  // ---- stage all weights L2 -> LDS once (overlaps first-batch PE) ----
  for (int i = tid * 8; i < LIMG; i += 4096)
    *(float4*)(wlds + i) = *(const float4*)(ws + i);

  bool staged = false;
  for (int it = 0; it < 8; ++it){
    // wave owns 32 rows: g=0 -> +l15, g=1 -> +16+l15
    const long long grow0 = ((long long)blockIdx.x * 8 + it) * 256 + wid * 32 + l15;

    // ---- PE + policy-1, both groups (pre-scaled to revolutions) ----
    float4 xv[2];
    xv[0] = ((const float4*)x)[grow0];
    xv[1] = ((const float4*)x)[grow0 + 16];
    f16x4 h0q[2][4], f1q[2][2];
    {
      const float4* pe4 = (const float4*)(bws + FB_PEW);
      const float4* p14 = (const float4*)(bws + FB_P1W);
      #pragma unroll
      for (int c = 0; c < 2; ++c)
        #pragma unroll
        for (int i = 0; i < 4; ++i){
          int d = c * 16 + lk * 4 + i;
          float4 w  = pe4[d]; float wb = bws[FB_PEB + d];
          float4 wp = p14[d]; float pb = bws[FB_P1B + d];
          #pragma unroll
          for (int g = 0; g < 2; ++g){
            float u = fmaf(xv[g].x,w.x,fmaf(xv[g].y,w.y,fmaf(xv[g].z,w.z,fmaf(xv[g].w,w.w,wb))));
            h0q[g][c][i]     = (f16)sin_pre(u);
            h0q[g][2 + c][i] = (f16)sin_pre(u + 0.25f);
            float z = fmaf(xv[g].x,wp.x,fmaf(xv[g].y,wp.y,fmaf(xv[g].z,wp.z,fmaf(xv[g].w,wp.w,pb))));
            f1q[g][c][i] = (f16)sin_pre(z);
          }
        }
    }

    // ---- policy-2 (L2 weights, kappa-permuted, 30/2pi folded) ----
    f16x4 f2q[2][2];
    #pragma unroll
    for (int ct = 0; ct < 2; ++ct){
      float4 b4 = *(const float4*)(bws + FB_P2 + ct * 16 + lk * 4);
      f16x8 wv = *(const f16x8*)(ws + OFF_WP2 + (ct * 16 + l15) * 32 + 8 * lk);
      #pragma unroll
      for (int g = 0; g < 2; ++g){
        f32x4 acc = {b4.x, b4.y, b4.z, b4.w};
        acc = __builtin_amdgcn_mfma_f32_16x16x32_f16(wv, SHUF8(f1q[g][0], f1q[g][1]), acc, 0, 0, 0);
        f2q[g][ct] = sin4p(acc);
      }
    }

    if (!staged){ __syncthreads(); staged = true; }   // weights ready (once)

    // ---- SIREN + bottleneck chain, all in registers ----
    f16x4 h1q[2][8];
    LAYER_LDS(8, 2, L_W1, FB_B1, h0q, h1q[g][ct] = sin4p(acc[g]))
    f16x4 h2s[2][16];
    LAYER_LDS(16, 4, L_W2, FB_B2, h1q, h2s[g][ct] = sin4p(acc[g]))
    f16x4 t1q[2][4];
    LAYER_LDS(4, 8, L_WF1, FB_F1, h2s, t1q[g][ct] = relu4(acc[g]))
    f16x4 t2q[2][4];
    LAYER_LDS(4, 2, L_WF2, FB_F2, t1q, t2q[g][ct] = relu4(acc[g]))
    // fc3 + residual in place: h2s <- relu(t2q@W3 + h2s)  (gate input)
    LAYER_LDS(16, 2, L_WF3, FB_F3, t2q, h2s[g][ct] = resrelu4(acc[g], h2s[g][ct]))

    // ---- gate + experts (swapped) + in-wave softmax/routing, per group ----
    {
      float4 gb = ((const float4*)(bws + FB_GE))[lk];
      #pragma unroll
      for (int g = 0; g < 2; ++g){
        f32x4 acc = {gb.x, gb.y, gb.z, gb.w};
        #pragma unroll
        for (int ks = 0; ks < 8; ++ks){
          f16x8 wv = *(const f16x8*)(ws + OFF_WGE + l15 * 288 + 32 * ks + 8 * lk);
          acc = __builtin_amdgcn_mfma_f32_16x16x32_f16(wv, SHUF8(h2s[g][2*ks], h2s[g][2*ks+1]), acc, 0, 0, 0);
        }
        {
          f16x8 wv = *(const f16x8*)(ws + OFF_WGE + l15 * 288 + 256 + 8 * lk);
          acc = __builtin_amdgcn_mfma_f32_16x16x32_f16(wv, SHUF8(f2q[g][0], f2q[g][1]), acc, 0, 0, 0);
        }
        // lane (l15,lk): gate rows m=4lk+i for row l15; lk<2 logits, lk>=2 preds
        float pred[4], lg[4];
        #pragma unroll
        for (int i = 0; i < 4; ++i) pred[i] = __shfl_xor(acc[i], 32);
        #pragma unroll
        for (int i = 0; i < 4; ++i) lg[i] = acc[i];
        if (lk == 1) lg[3] = -1e30f;           // gate row 7 = padding
        float mx = fmaxf(fmaxf(lg[0], lg[1]), fmaxf(lg[2], lg[3]));
        mx = fmaxf(mx, __shfl_xor(mx, 16));
        float s = 0.f, y = 0.f;
        #pragma unroll
        for (int i = 0; i < 4; ++i){ float p = __expf(lg[i] - mx); s += p; y += p * pred[i]; }
        s += __shfl_xor(s, 16); y += __shfl_xor(y, 16);
        if (lk == 0) out[grow0 + g * 16] = y / s;
      }
    }
  }
}

extern "C" void kernel_launch(void* const* d_in, const int* in_sizes, int n_in,
                              void* d_out, int out_size, void* d_ws, size_t ws_size,
                              hipStream_t stream)
{
  const float* x     = (const float*)d_in[0];
  const float* pe_w  = (const float*)d_in[1];
  const float* pe_b  = (const float*)d_in[2];
  const float* s1_w  = (const float*)d_in[3];
  const float* s1_b  = (const float*)d_in[4];
  const float* s2_w  = (const float*)d_in[5];
  const float* s2_b  = (const float*)d_in[6];
  const float* fc1_w = (const float*)d_in[7];
  const float* fc1_b = (const float*)d_in[8];
  const float* fc2_w = (const float*)d_in[9];
  const float* fc2_b = (const float*)d_in[10];
  const float* fc3_w = (const float*)d_in[11];
  const float* fc3_b = (const float*)d_in[12];
  const float* p1_w  = (const float*)d_in[13];
  const float* p1_b  = (const float*)d_in[14];
  const float* p2_w  = (const float*)d_in[15];
  const float* p2_b  = (const float*)d_in[16];
  const float* gate_w= (const float*)d_in[17];
  const float* gate_b= (const float*)d_in[18];
  const float* exp_w = (const float*)d_in[19];
  const float* exp_b = (const float*)d_in[20];
  f16* ws = (f16*)d_ws;

  convert_w<<<128, 256, 0, stream>>>(s1_w, s1_b, s2_w, s2_b, fc1_w, fc1_b, fc2_w, fc2_b,
                                     fc3_w, fc3_b, gate_w, gate_b, exp_w, exp_b, p2_w, p2_b,
                                     pe_w, pe_b, p1_w, p1_b, ws);
  moe_main<<<256, 512, 0, stream>>>(x, ws, (float*)d_out);
}

// Round 19
// 138.575 us; speedup vs baseline: 4.2614x; 4.2614x over previous
//
#include <hip/hip_runtime.h>

typedef _Float16 f16;
typedef _Float16 f16x2 __attribute__((ext_vector_type(2)));
typedef _Float16 f16x4 __attribute__((ext_vector_type(4)));
typedef _Float16 f16x8 __attribute__((ext_vector_type(8)));
typedef float f32x4 __attribute__((ext_vector_type(4)));

// ---- f16 weight arena in d_ws (units: halfs) ----
// [0, 77824): LDS image (ALL matmul weights), kappa-permuted + XOR-swizzled.
#define L_W1   0             // s1_w *30/2pi   [128][64]
#define L_W2   8192          // s2_w *30/2pi   [256][128]
#define L_WF1  40960         // fc1_w          [64][256]
#define L_WF2  57344         // fc2_w          [64][64]
#define L_WF3  61440         // fc3_w          [256][64]
#define LIMG   77824         // LDS image halfs (155648 B)
#define OFF_WGE 77824        // [16][288] kappa-permuted: rows 0-6 gate, 8-14 experts (L2)
#define OFF_WP2 82432        // p2_w *30/2pi  [32][32] kappa-permuted (L2)
#define TOTH    83456
// ---- fp32 arena at (float*)(ws + TOTH) ----
#define FB_B1  0
#define FB_B2  128
#define FB_F1  384
#define FB_F2  448
#define FB_F3  512
#define FB_GE  768           // gate_b(0..6), 0, exp_b(8..14), 0
#define FB_P2  784
#define FB_PEW 816           // pe_w * 1/2pi   [32][4]
#define FB_PEB 944           // pe_b * 1/2pi   [32]
#define FB_P1W 976           // p1_w * 30/2pi  [32][4]
#define FB_P1B 1104          // p1_b * 30/2pi  [32]
#define FBTOT  1136

#define SIREN_SCL 4.77464829275686f   // 30/(2*pi)
#define INV2PI    0.15915494309189535f

__device__ __forceinline__ float sin_pre(float v){   // v in revolutions
  return __builtin_amdgcn_sinf(__builtin_amdgcn_fractf(v));
}
__device__ __forceinline__ int permk(int k){
  return 16 * ((k & 7) >> 2) + ((k >> 3) & 3) * 4 + (k & 3);
}

// ---------- weight conversion (identical to R10/R14) ----------
__global__ void convert_w(const float* __restrict__ s1w, const float* __restrict__ s1b,
                          const float* __restrict__ s2w, const float* __restrict__ s2b,
                          const float* __restrict__ f1w, const float* __restrict__ f1b,
                          const float* __restrict__ f2w, const float* __restrict__ f2b,
                          const float* __restrict__ f3w, const float* __restrict__ f3b,
                          const float* __restrict__ gw,  const float* __restrict__ gb,
                          const float* __restrict__ ew,  const float* __restrict__ eb,
                          const float* __restrict__ p2w, const float* __restrict__ p2b,
                          const float* __restrict__ pew, const float* __restrict__ peb,
                          const float* __restrict__ p1w, const float* __restrict__ p1b,
                          f16* __restrict__ ws)
{
  int stride = gridDim.x * blockDim.x;
  int t0 = blockIdx.x * blockDim.x + threadIdx.x;
  for (int i = t0; i < TOTH; i += stride){
    float v;
    if (i < L_W2){
      int r = i >> 6, s = i & 63, k = s ^ ((r & 7) << 3);
      v = SIREN_SCL * s1w[(r << 6) + (k & 32) + permk(k & 31)];
    } else if (i < L_WF1){
      int j = i - L_W2, r = j >> 7, s = j & 127, k = s ^ ((r & 7) << 3);
      v = SIREN_SCL * s2w[(r << 7) + (k & 96) + permk(k & 31)];
    } else if (i < L_WF2){
      int j = i - L_WF1, r = j >> 8, s = j & 255, k = s ^ ((r & 7) << 3);
      v = f1w[(r << 8) + (k & 224) + permk(k & 31)];
    } else if (i < L_WF3){
      int j = i - L_WF2, r = j >> 6, s = j & 63, k = s ^ ((r & 7) << 3);
      v = f2w[(r << 6) + (k & 32) + permk(k & 31)];
    } else if (i < OFF_WGE){
      int j = i - L_WF3, r = j >> 6, s = j & 63, k = s ^ ((r & 7) << 3);
      v = f3w[(r << 6) + (k & 32) + permk(k & 31)];
    } else if (i < OFF_WP2){
      int j = i - OFF_WGE, r = j / 288, k = j - r * 288;
      int p = (k & ~31) + permk(k & 31);
      v = (r < 7) ? gw[r * 288 + p]
        : ((r >= 8 && r < 15 && p < 256) ? ew[(r - 8) * 256 + p] : 0.f);
    } else {
      int j = i - OFF_WP2, r = j >> 5, k = j & 31;
      v = SIREN_SCL * p2w[(r << 5) + permk(k)];
    }
    ws[i] = (f16)v;
  }
  float* bws = (float*)(ws + TOTH);
  for (int i = t0; i < FBTOT; i += stride){
    float v;
    if (i < 128)      v = SIREN_SCL * s1b[i];
    else if (i < 384) v = SIREN_SCL * s2b[i - 128];
    else if (i < 448) v = f1b[i - 384];
    else if (i < 512) v = f2b[i - 448];
    else if (i < 768) v = f3b[i - 512];
    else if (i < 784){ int j = i - 768;
      v = (j < 7) ? gb[j] : ((j >= 8 && j < 15) ? eb[j - 8] : 0.0f); }
    else if (i < 816) v = SIREN_SCL * p2b[i - 784];
    else if (i < 944) v = INV2PI * pew[i - FB_PEW];
    else if (i < 976) v = INV2PI * peb[i - FB_PEB];
    else if (i < 1104) v = SIREN_SCL * p1w[i - FB_P1W];
    else v = SIREN_SCL * p1b[i - FB_P1B];
    bws[i] = v;
  }
}

// packed f32->f16x2 conversion (R18 verified: absmax unchanged at 1.95e-3)
__device__ __forceinline__ f16x4 pk4(float a, float b, float c, float d){
  f16x2 lo = __builtin_bit_cast(f16x2, __builtin_amdgcn_cvt_pkrtz(a, b));
  f16x2 hi = __builtin_bit_cast(f16x2, __builtin_amdgcn_cvt_pkrtz(c, d));
  return __builtin_shufflevector(lo, hi, 0, 1, 2, 3);
}
__device__ __forceinline__ f16x4 sin4p(f32x4 a){
  return pk4(sin_pre(a[0]), sin_pre(a[1]), sin_pre(a[2]), sin_pre(a[3]));
}
__device__ __forceinline__ f16x4 relu4(f32x4 a){
  return pk4(fmaxf(a[0],0.f), fmaxf(a[1],0.f), fmaxf(a[2],0.f), fmaxf(a[3],0.f));
}
__device__ __forceinline__ f16x4 resrelu4(f32x4 a, f16x4 old){
  return pk4(fmaxf(a[0]+(float)old[0],0.f), fmaxf(a[1]+(float)old[1],0.f),
             fmaxf(a[2]+(float)old[2],0.f), fmaxf(a[3]+(float)old[3],0.f));
}
#define SHUF8(A_, B_) __builtin_shufflevector(A_, B_, 0, 1, 2, 3, 4, 5, 6, 7)

// AGPR stash (unified file; arch-VGPR alloc caps at 128, AGPRs idle).
// Protocol: 32 writes at s2, 32 reads at fc1 entry — ONCE each (R14's mistake
// was re-reading per-ct inside fc1's loop: ~400 ops -> 64 ops).
__device__ __forceinline__ void ag_w(float& a0, float& a1, f16x4 v){
  float2 f = __builtin_bit_cast(float2, v);
  asm("v_accvgpr_write_b32 %0, %2\n\tv_accvgpr_write_b32 %1, %3"
      : "=a"(a0), "=a"(a1) : "v"(f.x), "v"(f.y));
}
__device__ __forceinline__ f16x4 ag_r(float a0, float a1){
  float2 f;
  asm("v_accvgpr_read_b32 %0, %2\n\tv_accvgpr_read_b32 %1, %3"
      : "=v"(f.x), "=v"(f.y) : "a"(a0), "a"(a1));
  return __builtin_bit_cast(f16x4, f);
}

// 32 rows/wave, 2 row-groups; all matmul weights in LDS (152KB, 1 block/CU).
__global__ __launch_bounds__(512, 2) void moe_main(
    const float* __restrict__ x,
    const f16* __restrict__ ws, float* __restrict__ out)
{
  const float* bws = (const float*)(ws + TOTH);
  __shared__ __align__(16) f16 wlds[LIMG];   // 155648 B -> 1 block/CU, 8 waves

  const int tid = threadIdx.x;
  const int lane = tid & 63, wid = tid >> 6;
  const int l15 = lane & 15, lk = lane >> 4;
  const int swzh = (l15 & 7) << 3;
  const long long grow0 = (long long)blockIdx.x * 256 + wid * 32 + l15;

  float ag[32];                              // AGPR stash (all indices constant)

  // ---- stage all weights L2 -> LDS (overlaps PE below) ----
  for (int i = tid * 8; i < LIMG; i += 4096)
    *(float4*)(wlds + i) = *(const float4*)(ws + i);

  // ---- PE + policy-1, both groups (pre-scaled to revolutions) ----
  float4 xv[2];
  xv[0] = ((const float4*)x)[grow0];
  xv[1] = ((const float4*)x)[grow0 + 16];
  f16x4 h0q[2][4], f1q[2][2];
  {
    const float4* pe4 = (const float4*)(bws + FB_PEW);
    const float4* p14 = (const float4*)(bws + FB_P1W);
    #pragma unroll
    for (int c = 0; c < 2; ++c)
      #pragma unroll
      for (int i = 0; i < 4; ++i){
        int d = c * 16 + lk * 4 + i;
        float4 w  = pe4[d]; float wb = bws[FB_PEB + d];
        float4 wp = p14[d]; float pb = bws[FB_P1B + d];
        #pragma unroll
        for (int g = 0; g < 2; ++g){
          float u = fmaf(xv[g].x,w.x,fmaf(xv[g].y,w.y,fmaf(xv[g].z,w.z,fmaf(xv[g].w,w.w,wb))));
          h0q[g][c][i]     = (f16)sin_pre(u);
          h0q[g][2 + c][i] = (f16)sin_pre(u + 0.25f);
          float z = fmaf(xv[g].x,wp.x,fmaf(xv[g].y,wp.y,fmaf(xv[g].z,wp.z,fmaf(xv[g].w,wp.w,pb))));
          f1q[g][c][i] = (f16)sin_pre(z);
        }
      }
  }

  // ---- policy-2 (L2 weights, kappa-permuted) ----
  f16x4 f2q[2][2];
  #pragma unroll
  for (int ct = 0; ct < 2; ++ct){
    float4 b4 = *(const float4*)(bws + FB_P2 + ct * 16 + lk * 4);
    f16x8 wv = *(const f16x8*)(ws + OFF_WP2 + (ct * 16 + l15) * 32 + 8 * lk);
    #pragma unroll
    for (int g = 0; g < 2; ++g){
      f32x4 acc = {b4.x, b4.y, b4.z, b4.w};
      acc = __builtin_amdgcn_mfma_f32_16x16x32_f16(wv, SHUF8(f1q[g][0], f1q[g][1]), acc, 0, 0, 0);
      f2q[g][ct] = sin4p(acc);
    }
  }

  __syncthreads();   // weights staged (the only barrier)

  // ---- s1 (LDS weights, paired) ----
  f16x4 h1q[2][8];
  #pragma unroll
  for (int ct = 0; ct < 8; ++ct){
    float4 b4 = *(const float4*)(bws + FB_B1 + ct * 16 + lk * 4);
    f32x4 acc[2]; acc[0] = (f32x4){b4.x,b4.y,b4.z,b4.w}; acc[1] = acc[0];
    #pragma unroll
    for (int ks = 0; ks < 2; ++ks){
      f16x8 wv = *(const f16x8*)(wlds + L_W1 + (ct*16+l15)*64 + ((32*ks + 8*lk) ^ swzh));
      #pragma unroll
      for (int g = 0; g < 2; ++g)
        acc[g] = __builtin_amdgcn_mfma_f32_16x16x32_f16(wv, SHUF8(h0q[g][2*ks], h0q[g][2*ks+1]), acc[g], 0, 0, 0);
    }
    h1q[0][ct] = sin4p(acc[0]);
    h1q[1][ct] = sin4p(acc[1]);
  }

  // ---- s2 (LDS weights, paired): g0 -> regs, g1 -> AGPR stash (32 writes) ----
  f16x4 h2s0[16];
  #pragma unroll
  for (int ct = 0; ct < 16; ++ct){
    float4 b4 = *(const float4*)(bws + FB_B2 + ct * 16 + lk * 4);
    f32x4 acc[2]; acc[0] = (f32x4){b4.x,b4.y,b4.z,b4.w}; acc[1] = acc[0];
    #pragma unroll
    for (int ks = 0; ks < 4; ++ks){
      f16x8 wv = *(const f16x8*)(wlds + L_W2 + (ct*16+l15)*128 + ((32*ks + 8*lk) ^ swzh));
      #pragma unroll
      for (int g = 0; g < 2; ++g)
        acc[g] = __builtin_amdgcn_mfma_f32_16x16x32_f16(wv, SHUF8(h1q[g][2*ks], h1q[g][2*ks+1]), acc[g], 0, 0, 0);
    }
    h2s0[ct] = sin4p(acc[0]);
    ag_w(ag[2*ct], ag[2*ct+1], sin4p(acc[1]));
  }

  // ---- fc1 entry: h1q dead -> pull ALL g1 quads back ONCE (32 reads) ----
  f16x4 h2g1[16];
  #pragma unroll
  for (int q = 0; q < 16; ++q) h2g1[q] = ag_r(ag[2*q], ag[2*q+1]);

  // ---- fc1 (LDS weights, both groups from regs) ----
  f16x4 t1q[2][4];
  #pragma unroll
  for (int ct = 0; ct < 4; ++ct){
    float4 b4 = *(const float4*)(bws + FB_F1 + ct * 16 + lk * 4);
    f32x4 acc[2]; acc[0] = (f32x4){b4.x,b4.y,b4.z,b4.w}; acc[1] = acc[0];
    #pragma unroll
    for (int ks = 0; ks < 8; ++ks){
      f16x8 wv = *(const f16x8*)(wlds + L_WF1 + (ct*16+l15)*256 + ((32*ks + 8*lk) ^ swzh));
      acc[0] = __builtin_amdgcn_mfma_f32_16x16x32_f16(wv, SHUF8(h2s0[2*ks], h2s0[2*ks+1]), acc[0], 0, 0, 0);
      acc[1] = __builtin_amdgcn_mfma_f32_16x16x32_f16(wv, SHUF8(h2g1[2*ks], h2g1[2*ks+1]), acc[1], 0, 0, 0);
    }
    t1q[0][ct] = relu4(acc[0]);
    t1q[1][ct] = relu4(acc[1]);
  }

  // ---- fc2 (LDS weights) ----
  f16x4 t2q[2][4];
  #pragma unroll
  for (int ct = 0; ct < 4; ++ct){
    float4 b4 = *(const float4*)(bws + FB_F2 + ct * 16 + lk * 4);
    f32x4 acc[2]; acc[0] = (f32x4){b4.x,b4.y,b4.z,b4.w}; acc[1] = acc[0];
    #pragma unroll
    for (int ks = 0; ks < 2; ++ks){
      f16x8 wv = *(const f16x8*)(wlds + L_WF2 + (ct*16+l15)*64 + ((32*ks + 8*lk) ^ swzh));
      #pragma unroll
      for (int g = 0; g < 2; ++g)
        acc[g] = __builtin_amdgcn_mfma_f32_16x16x32_f16(wv, SHUF8(t1q[g][2*ks], t1q[g][2*ks+1]), acc[g], 0, 0, 0);
    }
    t2q[0][ct] = relu4(acc[0]);
    t2q[1][ct] = relu4(acc[1]);
  }

  // ---- fc3 + residual in place (both groups in regs) ----
  #pragma unroll
  for (int ct = 0; ct < 16; ++ct){
    float4 b4 = *(const float4*)(bws + FB_F3 + ct * 16 + lk * 4);
    f32x4 acc[2]; acc[0] = (f32x4){b4.x,b4.y,b4.z,b4.w}; acc[1] = acc[0];
    #pragma unroll
    for (int ks = 0; ks < 2; ++ks){
      f16x8 wv = *(const f16x8*)(wlds + L_WF3 + (ct*16+l15)*64 + ((32*ks + 8*lk) ^ swzh));
      #pragma unroll
      for (int g = 0; g < 2; ++g)
        acc[g] = __builtin_amdgcn_mfma_f32_16x16x32_f16(wv, SHUF8(t2q[g][2*ks], t2q[g][2*ks+1]), acc[g], 0, 0, 0);
    }
    h2s0[ct] = resrelu4(acc[0], h2s0[ct]);
    h2g1[ct] = resrelu4(acc[1], h2g1[ct]);
  }

  // ---- gate + experts (swapped) + in-wave softmax/routing, per group ----
  {
    float4 gb = ((const float4*)(bws + FB_GE))[lk];
    #pragma unroll
    for (int g = 0; g < 2; ++g){
      f32x4 acc = {gb.x, gb.y, gb.z, gb.w};
      #pragma unroll
      for (int ks = 0; ks < 8; ++ks){
        f16x8 wv = *(const f16x8*)(ws + OFF_WGE + l15 * 288 + 32 * ks + 8 * lk);
        f16x8 bf = g ? SHUF8(h2g1[2*ks], h2g1[2*ks+1]) : SHUF8(h2s0[2*ks], h2s0[2*ks+1]);
        acc = __builtin_amdgcn_mfma_f32_16x16x32_f16(wv, bf, acc, 0, 0, 0);
      }
      {
        f16x8 wv = *(const f16x8*)(ws + OFF_WGE + l15 * 288 + 256 + 8 * lk);
        acc = __builtin_amdgcn_mfma_f32_16x16x32_f16(wv, SHUF8(f2q[g][0], f2q[g][1]), acc, 0, 0, 0);
      }
      float pred[4], lg[4];
      #pragma unroll
      for (int i = 0; i < 4; ++i) pred[i] = __shfl_xor(acc[i], 32);
      #pragma unroll
      for (int i = 0; i < 4; ++i) lg[i] = acc[i];
      if (lk == 1) lg[3] = -1e30f;             // gate row 7 = padding
      float mx = fmaxf(fmaxf(lg[0], lg[1]), fmaxf(lg[2], lg[3]));
      mx = fmaxf(mx, __shfl_xor(mx, 16));
      float s = 0.f, y = 0.f;
      #pragma unroll
      for (int i = 0; i < 4; ++i){ float p = __expf(lg[i] - mx); s += p; y += p * pred[i]; }
      s += __shfl_xor(s, 16); y += __shfl_xor(y, 16);
      if (lk == 0) out[grow0 + g * 16] = y / s;
    }
  }
}

extern "C" void kernel_launch(void* const* d_in, const int* in_sizes, int n_in,
                              void* d_out, int out_size, void* d_ws, size_t ws_size,
                              hipStream_t stream)
{
  const float* x     = (const float*)d_in[0];
  const float* pe_w  = (const float*)d_in[1];
  const float* pe_b  = (const float*)d_in[2];
  const float* s1_w  = (const float*)d_in[3];
  const float* s1_b  = (const float*)d_in[4];
  const float* s2_w  = (const float*)d_in[5];
  const float* s2_b  = (const float*)d_in[6];
  const float* fc1_w = (const float*)d_in[7];
  const float* fc1_b = (const float*)d_in[8];
  const float* fc2_w = (const float*)d_in[9];
  const float* fc2_b = (const float*)d_in[10];
  const float* fc3_w = (const float*)d_in[11];
  const float* fc3_b = (const float*)d_in[12];
  const float* p1_w  = (const float*)d_in[13];
  const float* p1_b  = (const float*)d_in[14];
  const float* p2_w  = (const float*)d_in[15];
  const float* p2_b  = (const float*)d_in[16];
  const float* gate_w= (const float*)d_in[17];
  const float* gate_b= (const float*)d_in[18];
  const float* exp_w = (const float*)d_in[19];
  const float* exp_b = (const float*)d_in[20];
  f16* ws = (f16*)d_ws;

  convert_w<<<128, 256, 0, stream>>>(s1_w, s1_b, s2_w, s2_b, fc1_w, fc1_b, fc2_w, fc2_b,
                                     fc3_w, fc3_b, gate_w, gate_b, exp_w, exp_b, p2_w, p2_b,
                                     pe_w, pe_b, p1_w, p1_b, ws);
  moe_main<<<524288 / 256, 512, 0, stream>>>(x, ws, (float*)d_out);
}